// Round 7
// baseline (379.489 us; speedup 1.0000x reference)
//
#include <hip/hip_runtime.h>
#include <hip/hip_bf16.h>

typedef __bf16 bf16x8 __attribute__((ext_vector_type(8)));
typedef __bf16 bf16x4 __attribute__((ext_vector_type(4)));
typedef float  f32x4  __attribute__((ext_vector_type(4)));

#define MFMA16(a, b, c) __builtin_amdgcn_mfma_f32_16x16x32_bf16((a), (b), (c), 0, 0, 0)

#define GLOBAL_AS(p) ((const __attribute__((address_space(1))) void*)(p))
#define LDS_AS(p)    ((__attribute__((address_space(3))) void*)(p))

// ---------------------------------------------------------------------------
// fp32 -> bf16 elementwise convert.  Each thread converts 8 elements.
// ---------------------------------------------------------------------------
__global__ __launch_bounds__(256) void cvt_bf16_kernel(const float* __restrict__ in,
                                                       __bf16* __restrict__ out)
{
    const int idx = blockIdx.x * 256 + threadIdx.x;
    const float4* p = (const float4*)in + (size_t)idx * 2;
    float4 a = p[0], b = p[1];
    bf16x8 o;
    o[0] = (__bf16)a.x; o[1] = (__bf16)a.y; o[2] = (__bf16)a.z; o[3] = (__bf16)a.w;
    o[4] = (__bf16)b.x; o[5] = (__bf16)b.y; o[6] = (__bf16)b.z; o[7] = (__bf16)b.w;
    ((bf16x8*)out)[idx] = o;
}

// ---------------------------------------------------------------------------
// All four weight transposes in ONE dispatch.  Bt[n][k] = (bf16)W[k][n].
// 1D grid of 9216 blocks, block (32,8):
//   [0,4096)    Wq  (2048x2048) -> Wqkvt[0..2048)
//   [4096,4608) Wk  (2048x256)  -> Wqkvt[2048..2304)
//   [4608,5120) Wv  (2048x256)  -> Wqkvt[2304..2560)
//   [5120,9216) Wo  (2048x2048) -> Wot
// ---------------------------------------------------------------------------
__global__ __launch_bounds__(256) void transpose_all_kernel(const float* __restrict__ Wq,
                                                            const float* __restrict__ Wk,
                                                            const float* __restrict__ Wv,
                                                            const float* __restrict__ Wo,
                                                            __bf16* __restrict__ Wqkvt,
                                                            __bf16* __restrict__ Wot)
{
    __shared__ float t[32][33];
    const int id = blockIdx.x;
    const float* W; __bf16* dst; int N, loc;
    if (id < 4096)      { W = Wq; dst = Wqkvt;                        N = 2048; loc = id; }
    else if (id < 4608) { W = Wk; dst = Wqkvt + (size_t)2048 * 2048;  N = 256;  loc = id - 4096; }
    else if (id < 5120) { W = Wv; dst = Wqkvt + (size_t)2304 * 2048;  N = 256;  loc = id - 4608; }
    else                { W = Wo; dst = Wot;                          N = 2048; loc = id - 5120; }
    const int nb = N >> 5;
    const int n0 = (loc % nb) * 32, k0 = (loc / nb) * 32;
    const int x = threadIdx.x, y = threadIdx.y;
#pragma unroll
    for (int r = 0; r < 4; ++r)
        t[y + r * 8][x] = W[(size_t)(k0 + y + r * 8) * N + n0 + x];
    __syncthreads();
#pragma unroll
    for (int r = 0; r < 4; ++r)
        dst[(size_t)(n0 + y + r * 8) * 2048 + k0 + x] = (__bf16)t[x][y + r * 8];
}

// ---------------------------------------------------------------------------
// bf16 transpose for V: vT[b][d][s] = qkv[b*2048+s][2304+d].
// ---------------------------------------------------------------------------
__global__ __launch_bounds__(256) void vt_kernel(const __bf16* __restrict__ qkv,
                                                 __bf16* __restrict__ vT)
{
    __shared__ __bf16 t[32][33];
    const int s0 = blockIdx.x * 32, d0 = blockIdx.y * 32, b = blockIdx.z;
    const int x = threadIdx.x, y = threadIdx.y;
#pragma unroll
    for (int r = 0; r < 4; ++r)
        t[y + r * 8][x] = qkv[(size_t)(b * 2048 + s0 + y + r * 8) * 2560 + 2304 + d0 + x];
    __syncthreads();
#pragma unroll
    for (int r = 0; r < 4; ++r)
        vT[(size_t)(b * 256 + d0 + y + r * 8) * 2048 + s0 + x] = t[x][y + r * 8];
}

// ---------------------------------------------------------------------------
// GEMM (m97 structure): C[M][N] = A[M][K] * Bt[N][K]^T, bf16 inputs.
// ---------------------------------------------------------------------------
template <typename TC>
__global__ __launch_bounds__(256) void gemm_bt(const __bf16* __restrict__ A,
                                               const __bf16* __restrict__ Bt,
                                               TC* __restrict__ C,
                                               int M, int N, int K)
{
    __shared__ __bf16 As[128 * 32];
    __shared__ __bf16 Bs[128 * 32];

    const int tid  = threadIdx.x;
    const int wave = tid >> 6, lane = tid & 63;
    const int quad = lane >> 4, l16 = lane & 15;
    const int wm = (wave >> 1) * 64, wn = (wave & 1) * 64;
    const int bm = blockIdx.y * 128, bn = blockIdx.x * 128;

    f32x4 acc[4][4] = {};

    for (int k0 = 0; k0 < K; k0 += 32) {
        __syncthreads();
#pragma unroll
        for (int c = 0; c < 2; ++c) {
            const int off = tid * 16 + c * 4096;
            const int row = off >> 6;
            const int kb  = (off & 63) >> 1;
            const __bf16* ga = A  + (size_t)(bm + row) * K + k0 + kb;
            const __bf16* gb = Bt + (size_t)(bn + row) * K + k0 + kb;
            __builtin_amdgcn_global_load_lds(GLOBAL_AS(ga), LDS_AS(As + (off >> 1)), 16, 0, 0);
            __builtin_amdgcn_global_load_lds(GLOBAL_AS(gb), LDS_AS(Bs + (off >> 1)), 16, 0, 0);
        }
        __syncthreads();

        bf16x8 af[4];
#pragma unroll
        for (int mi = 0; mi < 4; ++mi)
            af[mi] = *(const bf16x8*)&As[(wm + mi * 16 + l16) * 32 + quad * 8];
#pragma unroll
        for (int ni = 0; ni < 4; ++ni) {
            bf16x8 bfr = *(const bf16x8*)&Bs[(wn + ni * 16 + l16) * 32 + quad * 8];
#pragma unroll
            for (int mi = 0; mi < 4; ++mi)
                acc[mi][ni] = MFMA16(af[mi], bfr, acc[mi][ni]);
        }
    }
#pragma unroll
    for (int mi = 0; mi < 4; ++mi)
#pragma unroll
        for (int ni = 0; ni < 4; ++ni)
#pragma unroll
            for (int r = 0; r < 4; ++r) {
                int row = bm + wm + mi * 16 + quad * 4 + r;
                int col = bn + wn + ni * 16 + l16;
                C[(size_t)row * N + col] = (TC)acc[mi][ni][r];
            }
}

// ---------------------------------------------------------------------------
// RoPE in place on fused qkv[4096][2560], inline sincos (no table).
// q pre-scaled by log2(e)/16.  For t<32, i0 == t*4 so the k-part reuses cst.
// ---------------------------------------------------------------------------
__global__ __launch_bounds__(256) void rope_kernel(__bf16* __restrict__ qkv)
{
    const int bs = blockIdx.x;
    const int s = bs & 2047;
    const int t = threadIdx.x;
    const float QS = 0.09016843787599907f;   // log2(e) / sqrt(D)
    const float NF = -13.287712379549449f / 128.f;  // -log2(10000)/128

    const int hh = t >> 5, i0 = (t & 31) * 4;
    float cx[4], sx[4];
#pragma unroll
    for (int e = 0; e < 4; ++e) {
        float th = (float)s * exp2f((float)(i0 + e) * NF);
        sincosf(th, &sx[e], &cx[e]);
    }
    {
        __bf16* p = qkv + (size_t)bs * 2560 + hh * 256 + i0;
        bf16x4 x1 = *(const bf16x4*)p;
        bf16x4 x2 = *(const bf16x4*)(p + 128);
        bf16x4 o1, o2;
#pragma unroll
        for (int e = 0; e < 4; ++e) {
            o1[e] = (__bf16)(((float)x1[e] * cx[e] - (float)x2[e] * sx[e]) * QS);
            o2[e] = (__bf16)(((float)x2[e] * cx[e] + (float)x1[e] * sx[e]) * QS);
        }
        *(bf16x4*)p = o1;
        *(bf16x4*)(p + 128) = o2;
    }
    if (t < 32) {   // k: pairs j0..j0+3 with j0 = t*4 == i0 (same cst)
        __bf16* p = qkv + (size_t)bs * 2560 + 2048 + i0;
        bf16x4 x1 = *(const bf16x4*)p;
        bf16x4 x2 = *(const bf16x4*)(p + 128);
        bf16x4 o1, o2;
#pragma unroll
        for (int e = 0; e < 4; ++e) {
            o1[e] = (__bf16)((float)x1[e] * cx[e] - (float)x2[e] * sx[e]);
            o2[e] = (__bf16)((float)x2[e] * cx[e] + (float)x1[e] * sx[e]);
        }
        *(bf16x4*)p = o1;
        *(bf16x4*)(p + 128) = o2;
    }
}

// ---------------------------------------------------------------------------
// Flash attention, SPLIT-K x2 (static-max softmax makes partials additive:
// o = o0+o1, l = l0+l1, no max bookkeeping).  grid = (64, H, B):
// blockIdx.x -> (qt = 31-(bx>>1), kh = bx&1); block kh processes the 32-key
// tiles with parity kh (each half = qt+1 tiles, perfectly balanced).
// 32-key tiles, LDS 37.5 KB -> 4 blocks/CU = 4 waves/SIMD.
// Writes UNNORMALIZED bf16 partial O (po[kh]) + fp32 partial l (pl).
// ---------------------------------------------------------------------------
__global__ __launch_bounds__(256, 4) void attn_kernel(const __bf16* __restrict__ qkv,
                                                      const __bf16* __restrict__ vTg,
                                                      __bf16* __restrict__ po0,
                                                      __bf16* __restrict__ po1,
                                                      float* __restrict__ pl)
{
    __shared__ __bf16 Ks[32 * 256];    // 32 keys x 256 d (swizzled), 16 KB
    __shared__ __bf16 Vs[272 * 32];    // 256 d x 32 keys (swizzled) + 16 ones rows
    __shared__ __bf16 Ps[4][16][36];   // per-wave P [qrow][key], pad 32->36

    const int b = blockIdx.z, h = blockIdx.y;
    const int qt = 31 - (int)(blockIdx.x >> 1);
    const int kh = blockIdx.x & 1;
    const int q0 = qt * 64;
    const int tid  = threadIdx.x;
    const int wave = tid >> 6, lane = tid & 63;
    const int quad = lane >> 4, l16 = lane & 15;
    const int xork = l16 & 7;

    // ones rows for the l-tile (rows 256..271; staging never touches them)
    if (tid < 64) {
        bf16x8 one;
#pragma unroll
        for (int e = 0; e < 8; ++e) one[e] = (__bf16)1.0f;
        *(bf16x8*)&Vs[256 * 32 + tid * 8] = one;
    }

    // Q fragments (A-layout); q row stride 2560
    const int qrow = q0 + wave * 16 + l16;
    const __bf16* qptr = qkv + (size_t)(b * 2048 + qrow) * 2560 + h * 256;
    bf16x8 qf[8];
#pragma unroll
    for (int dc = 0; dc < 8; ++dc)
        qf[dc] = *(const bf16x8*)(qptr + dc * 32 + quad * 8);

    f32x4 oacc[17] = {};               // [16] = l-tile

    // staging precompute.  K: 32 rows x 32 chunks, 4 rounds.
    const int kKey0 = tid >> 5;                       // 0..7
    const int kC    = (tid & 31) ^ (kKey0 & 7);
    const __bf16* kstage0 = qkv + (size_t)b * 2048 * 2560 + 2048
                          + (size_t)kKey0 * 2560 + kC * 8;
    // V: 256 rows x 4 chunks, 4 rounds.  slot = c ^ (d&3).
    const int vD0 = tid >> 2;                         // 0..63
    const int vC  = (tid & 3) ^ (vD0 & 3);
    const __bf16* vstage0 = vTg + (size_t)b * 256 * 2048 + (size_t)vD0 * 2048 + vC * 8;

    int ckK[8];
#pragma unroll
    for (int dc = 0; dc < 8; ++dc) ckK[dc] = (dc * 4 + quad) ^ xork;
    const int chV = quad ^ (l16 & 3);   // V fragment slot (32-key rows, 4 chunks)

    for (int j0 = kh * 32; j0 < q0 + 64; j0 += 64) {
        __syncthreads();
        const __bf16* kst = kstage0 + (size_t)j0 * 2560;
        const __bf16* vst = vstage0 + j0;
#pragma unroll
        for (int p = 0; p < 4; ++p)
            __builtin_amdgcn_global_load_lds(GLOBAL_AS(kst + (size_t)p * 8 * 2560),
                                             LDS_AS(Ks + tid * 8 + p * 2048), 16, 0, 0);
#pragma unroll
        for (int p = 0; p < 4; ++p)
            __builtin_amdgcn_global_load_lds(GLOBAL_AS(vst + (size_t)p * 64 * 2048),
                                             LDS_AS(Vs + tid * 8 + p * 2048), 16, 0, 0);
        __syncthreads();   // vmcnt(0) drain -> tile visible

        // ---- S = Q K^T over 32 keys (2 n-tiles) ----
        f32x4 sc[2] = {};
#pragma unroll
        for (int nt = 0; nt < 2; ++nt) {
            const __bf16* krow = &Ks[(nt * 16 + l16) * 256];
#pragma unroll
            for (int dc = 0; dc < 8; ++dc) {
                bf16x8 kf = *(const bf16x8*)(krow + ckK[dc] * 8);
                sc[nt] = MFMA16(qf[dc], kf, sc[nt]);
            }
        }
        if (j0 >= q0) {   // diagonal region: causal mask (-1e30 -> exp2 == 0)
#pragma unroll
            for (int nt = 0; nt < 2; ++nt) {
                int key = j0 + nt * 16 + l16;
#pragma unroll
                for (int r = 0; r < 4; ++r) {
                    int row = q0 + wave * 16 + quad * 4 + r;
                    if (key > row) sc[nt][r] = -1e30f;
                }
            }
        }
        // ---- static-max softmax: p = exp2(s - 8) -> P LDS round-trip ----
#pragma unroll
        for (int nt = 0; nt < 2; ++nt)
#pragma unroll
            for (int r = 0; r < 4; ++r)
                Ps[wave][quad * 4 + r][nt * 16 + l16] = (__bf16)exp2f(sc[nt][r] - 8.f);
        bf16x8 pf = *(const bf16x8*)&Ps[wave][l16][quad * 8];
        // ---- O += P V (17 d-tiles; dt=16 accumulates l) ----
#pragma unroll
        for (int dt = 0; dt < 17; ++dt) {
            bf16x8 vf = *(const bf16x8*)&Vs[(dt * 16 + l16) * 32 + chV * 8];
            oacc[dt] = MFMA16(pf, vf, oacc[dt]);
        }
    }
    // ---- store unnormalized partials ----
    __bf16* pob = kh ? po1 : po0;
    const int rowb = q0 + wave * 16 + quad * 4;
#pragma unroll
    for (int dt = 0; dt < 16; ++dt)
#pragma unroll
        for (int r = 0; r < 4; ++r) {
            int col = h * 256 + dt * 16 + l16;
            pob[(size_t)(b * 2048 + rowb + r) * 2048 + col] = (__bf16)oacc[dt][r];
        }
    if (l16 == 0) {
        float* plp = pl + (size_t)((kh * 2 + b) * 8 + h) * 2048 + rowb;
#pragma unroll
        for (int r = 0; r < 4; ++r) plp[r] = oacc[16][r];
    }
}

// ---------------------------------------------------------------------------
// Combine split-K partials IN-PLACE: ob (== po0 region) = (po0+po1)/(l0+l1).
// grid 4096 (one block per (b,row)), 256 thr x 8 cols.
// ---------------------------------------------------------------------------
__global__ __launch_bounds__(256) void combine_kernel(__bf16* __restrict__ po0,
                                                      const __bf16* __restrict__ po1,
                                                      const float* __restrict__ pl)
{
    const int row = blockIdx.x;            // b*2048 + s
    const int b = row >> 11, s = row & 2047;
    const int t = threadIdx.x;
    const int h = (t * 8) >> 8;
    const float l0 = pl[(size_t)((0 * 2 + b) * 8 + h) * 2048 + s];
    const float l1 = pl[(size_t)((1 * 2 + b) * 8 + h) * 2048 + s];
    const float inv = 1.f / (l0 + l1);
    const size_t idx = (size_t)row * 256 + t;
    bf16x8 a = ((const bf16x8*)po0)[idx];
    bf16x8 c = ((const bf16x8*)po1)[idx];
    bf16x8 o;
#pragma unroll
    for (int e = 0; e < 8; ++e)
        o[e] = (__bf16)(((float)a[e] + (float)c[e]) * inv);
    ((bf16x8*)po0)[idx] = o;
}

// ---------------------------------------------------------------------------
// Workspace layout (byte offsets, MiB):
//   hb    [4096][2048] bf16 @  0   (16)  hidden bf16; DEAD after gemm1 -> po1
//   qkv   [4096][2560] bf16 @ 16   (20)
//   vT    [2][256][2048]    @ 36   ( 2)
//   ob    [4096][2048] bf16 @ 38   (16)  po0 = ob (combine normalizes in place)
//   Wqkvt [2560][2048] bf16 @ 54   (10)  DEAD after gemm1 -> pl (256 KB)
//   Wot   [2048][2048] bf16 @ 64   ( 8)  total 72 MiB
// ---------------------------------------------------------------------------
extern "C" void kernel_launch(void* const* d_in, const int* in_sizes, int n_in,
                              void* d_out, int out_size, void* d_ws, size_t ws_size,
                              hipStream_t stream)
{
    (void)in_sizes; (void)n_in; (void)out_size; (void)ws_size;
    const float* hidden = (const float*)d_in[0];
    const float* Wq = (const float*)d_in[3];
    const float* Wk = (const float*)d_in[4];
    const float* Wv = (const float*)d_in[5];
    const float* Wo = (const float*)d_in[6];

    char* ws = (char*)d_ws;
    __bf16* hb    = (__bf16*)(ws);
    __bf16* qkv   = (__bf16*)(ws + (16u << 20));
    __bf16* vTb   = (__bf16*)(ws + (36u << 20));
    __bf16* ob    = (__bf16*)(ws + (38u << 20));
    __bf16* Wqkvt = (__bf16*)(ws + (54u << 20));
    __bf16* Wot   = (__bf16*)(ws + (64u << 20));
    __bf16* po1   = hb;                      // dead after gemm1
    float*  pl    = (float*)Wqkvt;           // dead after gemm1
    float* out = (float*)d_out;

    dim3 blk(256);
    dim3 tblk(32, 8);
    cvt_bf16_kernel<<<dim3(4096), blk, 0, stream>>>(hidden, hb);
    transpose_all_kernel<<<dim3(9216), tblk, 0, stream>>>(Wq, Wk, Wv, Wo, Wqkvt, Wot);
    gemm_bt<__bf16><<<dim3(20, 32), blk, 0, stream>>>(hb, Wqkvt, qkv, 4096, 2560, 2048);
    rope_kernel<<<dim3(4096), blk, 0, stream>>>(qkv);
    vt_kernel<<<dim3(64, 8, 2), tblk, 0, stream>>>(qkv, vTb);
    attn_kernel<<<dim3(64, 8, 2), blk, 0, stream>>>(qkv, vTb, ob, po1, pl);
    combine_kernel<<<dim3(4096), blk, 0, stream>>>(ob, po1, pl);
    gemm_bt<float><<<dim3(16, 32), blk, 0, stream>>>(ob, Wot, out, 4096, 2048, 2048);
}